// Round 4
// baseline (123.840 us; speedup 1.0000x reference)
//
#include <hip/hip_runtime.h>
#include <hip/hip_bf16.h>

// KAN harmonic-basis GEMM, v4.
// out[b,h] = sum_{d,f} basis(x[b,d])[f] * W[d,f,h] + sum_d b[d,h]
//
// f=0 + bias -> fp32 partials c_part[8][256], summed in GEMM epilogue.
// f=1..10    -> bf16 MFMA GEMM, M=16384, N=256, K=2560.
// Block 128x128, 4 waves, wave-tile 64x64 (4x4 fragments) -> B-frag reuse x4.
// A generated per HALF-dtile (5 harmonics x 32 d = 160 k) into LDS,
// double-buffered (2x40 KB): gen of half h+1 overlaps MFMA burst on half h,
// one barrier per 80 MFMAs. Harmonic halves are self-contained from one
// sincos: half0 = [s1,c1,s3,c3,s5], half1 = [s2,c2,s4,c4,c5] (prep reorders
// W to match). B read directly from L2-resident Wfrag (fragment-linear),
// primed at body start + 1-step register prefetch.

#define HOUT 256
#define DDIM 256
#define KTOT 2560
#define NKT  80

typedef __bf16 bf16x8 __attribute__((ext_vector_type(8)));
typedef float floatx4 __attribute__((ext_vector_type(4)));

__device__ __forceinline__ unsigned short f2bf(float f) {
    unsigned int u = __float_as_uint(f);
    return (unsigned short)((u + 0x7FFFu + ((u >> 16) & 1u)) >> 16);
}

__device__ __forceinline__ unsigned int pkbf(float a, float b) {
    __hip_bfloat162 r = __float22bfloat162_rn(make_float2(a, b));
    return *reinterpret_cast<unsigned int*>(&r);
}

// hs-order within a dtile: q 0..4 = [s1,c1,s3,c3,s5], q 5..9 = [s2,c2,s4,c4,c5]
// W's f index: sin(kx) -> 2k-1, cos(kx) -> 2k   (f=0 is the constant term)
__device__ __constant__ int FMAP[10] = {1, 2, 5, 6, 9, 3, 4, 7, 8, 10};

// grid 88 x 256 threads.
// blocks [0,80): kt; Wfrag[kt][n][dd] = bf16(W[(kt/10)*32+dd][FMAP[kt%10]][n])
// blocks [80,88): p = bid-80; c_part[p][h] = sum_{d in p*32..+32} W[d][0][h]+b[d][h]
__global__ void prep_kernel(const float* __restrict__ W, const float* __restrict__ bias,
                            unsigned short* __restrict__ Wfrag, float* __restrict__ c_part) {
    const int bid = blockIdx.x;
    const int t = threadIdx.x;
    if (bid < NKT) {
        const int kt = bid;
        const int dtile = kt / 10;
        const int f = FMAP[kt - dtile * 10];
        const float* wsrc = W + ((size_t)(dtile * 32) * 11 + f) * 256 + t;
        union { unsigned short s[32]; int4 v[4]; } buf;
#pragma unroll
        for (int dd = 0; dd < 32; ++dd)
            buf.s[dd] = f2bf(wsrc[(size_t)dd * 11 * 256]);
        int4* dst = (int4*)(Wfrag + ((size_t)kt * 256 + t) * 32);
#pragma unroll
        for (int v = 0; v < 4; ++v) dst[v] = buf.v[v];
    } else {
        const int p = bid - NKT;
        float acc = 0.f;
#pragma unroll
        for (int dd = 0; dd < 32; ++dd) {
            const int d = p * 32 + dd;
            acc += W[(size_t)(d * 11) * 256 + t] + bias[(size_t)d * 256 + t];
        }
        c_part[p * 256 + t] = acc;
    }
}

// 5 harmonics of one half for one x value.
__device__ __forceinline__ void harm5(float xv, float v[5], int halfsel) {
    float s1, c1;
    __sincosf(xv, &s1, &c1);
    const float t2 = c1 + c1;
    const float c2 = __builtin_fmaf(t2, c1, -1.f);
    const float tc = c2 + c2;
    if (halfsel == 0) {
        const float s3 = __builtin_fmaf(tc, s1, s1);    // sin3x = 2cos2x sinx + sinx
        const float c3 = __builtin_fmaf(tc, c1, -c1);   // cos3x = 2cos2x cosx - cosx
        const float s5 = __builtin_fmaf(tc, s3, -s1);   // sin5x = 2cos2x sin3x - sinx
        v[0] = s1; v[1] = c1; v[2] = s3; v[3] = c3; v[4] = s5;
    } else {
        const float s2 = t2 * s1;                       // sin2x = 2 sinx cosx
        const float s4 = tc * s2;                       // sin4x = 2cos2x sin2x
        const float c4 = __builtin_fmaf(tc, c2, -1.f);  // cos4x = 2cos2x cos2x - 1
        const float c5 = __builtin_fmaf(c4, c1, -s4 * s1); // cos5x = c4 c1 - s4 s1
        v[0] = s2; v[1] = c2; v[2] = s4; v[3] = c4; v[4] = c5;
    }
}

// Generate one octet (8 consecutive d) x 5 harmonics, write 5 fragment slots.
// dst = &Abuf[tile_m*512 + slot*8]; hs stride = 8 tiles * 512 shorts = 4096.
__device__ __forceinline__ void gen_octet(unsigned short* dst, const float4 xa,
                                          const float4 xb, int halfsel) {
    union { unsigned int u[4]; int4 q; } fr[5];
    const float xs[8] = {xa.x, xa.y, xa.z, xa.w, xb.x, xb.y, xb.z, xb.w};
#pragma unroll
    for (int p = 0; p < 4; ++p) {
        float va[5], vb[5];
        harm5(xs[2 * p], va, halfsel);
        harm5(xs[2 * p + 1], vb, halfsel);
#pragma unroll
        for (int hs = 0; hs < 5; ++hs) fr[hs].u[p] = pkbf(va[hs], vb[hs]);
    }
#pragma unroll
    for (int hs = 0; hs < 5; ++hs)
        *(int4*)(dst + hs * 4096) = fr[hs].q;
}

__global__ __launch_bounds__(256)
void kan_gemm(const float* __restrict__ x, const unsigned short* __restrict__ Wfrag,
              const float* __restrict__ c_part, float* __restrict__ out) {
    // [buf][ (hs*8 + tile_m)*512 + slot*8 + j ], slot = (m&15) + 16*(dd>>3)
    __shared__ unsigned short As[2][5 * 8 * 512];   // 2 x 40 KB = 80 KB

    const int t = threadIdx.x;
    const int m0 = blockIdx.x * 128;
    const int h0 = blockIdx.y * 128;

    const int lane = t & 63;
    const int wave = t >> 6;
    const int wr = wave >> 1;        // 64-row band
    const int wc = wave & 1;         // 64-col band
    const int l15 = lane & 15;
    const int koff = lane >> 4;

    // gen assignment: row gm = t&127, octets gob, gob+1 (dd = gob*8 .. gob*8+16)
    const int gm = t & 127;
    const int gob = (t >> 7) * 2;
    const int goff0 = (gm >> 4) * 512 + ((gm & 15) + 16 * gob) * 8;
    const int goff1 = (gm >> 4) * 512 + ((gm & 15) + 16 * (gob + 1)) * 8;

    floatx4 acc[4][4];
#pragma unroll
    for (int il = 0; il < 4; ++il)
#pragma unroll
        for (int j = 0; j < 4; ++j)
            acc[il][j] = (floatx4){0.f, 0.f, 0.f, 0.f};

    const float* xrow = x + (size_t)(m0 + gm) * DDIM + gob * 8;
    const unsigned short* bbase = Wfrag + (size_t)(h0 + wc * 64 + l15) * 32 + koff * 8;

    float4 xq0, xq1, xq2, xq3;

    // prologue: gen half 0 (dtile 0) into buf 0
    {
        const float* xp = xrow;
        xq0 = *(const float4*)(xp);
        xq1 = *(const float4*)(xp + 4);
        xq2 = *(const float4*)(xp + 8);
        xq3 = *(const float4*)(xp + 12);
        gen_octet(&As[0][goff0], xq0, xq1, 0);
        gen_octet(&As[0][goff1], xq2, xq3, 0);
    }
    __syncthreads();

    for (int h = 0; h < 16; ++h) {
        unsigned short* bufc = As[h & 1];
        const unsigned short* bkt = bbase + (size_t)(5 * h) * 8192;

        bf16x8 bc[4], bn[4], ac[4], an[4];
        // prime B (kt = 5h) and A (hs = 0); latency hidden under the gen burst
#pragma unroll
        for (int j = 0; j < 4; ++j)
            bc[j] = *(const bf16x8*)(bkt + j * 512);
#pragma unroll
        for (int il = 0; il < 4; ++il)
            ac[il] = *(const bf16x8*)(&bufc[(wr * 4 + il) * 512 + lane * 8]);

        // gen half h+1 into the other buffer
        if (h < 15) {
            const int hn = h + 1;
            if ((hn & 1) == 0) {   // new dtile -> load its x (wave-uniform branch)
                const float* xp = xrow + (hn >> 1) * 32;
                xq0 = *(const float4*)(xp);
                xq1 = *(const float4*)(xp + 4);
                xq2 = *(const float4*)(xp + 8);
                xq3 = *(const float4*)(xp + 12);
            }
            unsigned short* bufn = As[hn & 1];
            gen_octet(&bufn[goff0], xq0, xq1, hn & 1);
            gen_octet(&bufn[goff1], xq2, xq3, hn & 1);
        }

        // 5 k-steps, 16 MFMA each, 1-step register prefetch of A and B
#pragma unroll
        for (int hs = 0; hs < 5; ++hs) {
            if (hs < 4) {
#pragma unroll
                for (int j = 0; j < 4; ++j)
                    bn[j] = *(const bf16x8*)(bkt + (size_t)(hs + 1) * 8192 + j * 512);
#pragma unroll
                for (int il = 0; il < 4; ++il)
                    an[il] = *(const bf16x8*)(&bufc[((hs + 1) * 8 + wr * 4 + il) * 512 + lane * 8]);
            }
#pragma unroll
            for (int il = 0; il < 4; ++il)
#pragma unroll
                for (int j = 0; j < 4; ++j)
                    acc[il][j] = __builtin_amdgcn_mfma_f32_16x16x32_bf16(ac[il], bc[j], acc[il][j], 0, 0, 0);
            if (hs < 4) {
#pragma unroll
                for (int j = 0; j < 4; ++j) bc[j] = bn[j];
#pragma unroll
                for (int il = 0; il < 4; ++il) ac[il] = an[il];
            }
        }
        __syncthreads();
    }

    // epilogue: C/D layout col = lane&15, row = koff*4 + reg
    float cj[4];
#pragma unroll
    for (int j = 0; j < 4; ++j) {
        const int col = h0 + wc * 64 + j * 16 + l15;
        float s = 0.f;
#pragma unroll
        for (int p = 0; p < 8; ++p) s += c_part[p * 256 + col];
        cj[j] = s;
    }
#pragma unroll
    for (int il = 0; il < 4; ++il) {
        const int row0 = m0 + (wr * 4 + il) * 16 + koff * 4;
#pragma unroll
        for (int j = 0; j < 4; ++j) {
            const int col = h0 + wc * 64 + j * 16 + l15;
#pragma unroll
            for (int r = 0; r < 4; ++r)
                out[(size_t)(row0 + r) * HOUT + col] = acc[il][j][r] + cj[j];
        }
    }
}

extern "C" void kernel_launch(void* const* d_in, const int* in_sizes, int n_in,
                              void* d_out, int out_size, void* d_ws, size_t ws_size,
                              hipStream_t stream) {
    const float* x = (const float*)d_in[0];
    const float* W = (const float*)d_in[1];
    const float* b = (const float*)d_in[2];
    float* out = (float*)d_out;

    unsigned short* Wfrag = (unsigned short*)d_ws;                      // 1,310,720 B
    float* c_part = (float*)((char*)d_ws + (size_t)NKT * 256 * 32 * 2); // 8 KB

    prep_kernel<<<NKT + 8, 256, 0, stream>>>(W, b, Wfrag, c_part);
    kan_gemm<<<dim3(16384 / 128, 2), 256, 0, stream>>>(x, Wfrag, c_part, out);
}